// Round 9
// baseline (217.904 us; speedup 1.0000x reference)
//
#include <hip/hip_runtime.h>

#define L_IN   4000
#define CIN    512
#define KSZ    16
#define LOUT   31992   // 8 * 3999
#define NQ     3999    // valid q: 0..3998
#define NCH    8       // ci chunks per sample
#define CPC    64      // ci per chunk
#define QHALF  2000    // q positions per half-block
#define PSTR   32768   // partial stride per (b, chunk), floats
#define PBSTR  (NCH * PSTR)

// DIAGNOSTIC ROUND: identical computation to R8 but the accumulation pass
// runs TWICE (acc *= 0.5f at the end -> bit-exact same output). Purpose:
// push kernel dur above the harness's 75 us fill rows so its counter row
// (FETCH/WRITE/VALUBusy/Occupancy) finally appears in the top-5 table and
// discriminates the surviving theories for the config-invariant ~60 us wall:
//   FETCH ~2x input  -> true HBM read-efficiency/MLP cap
//   FETCH ~1x input  -> LLC serves repeat; kernel is latency-bound, not BW
//   VALUBusy >= 40%  -> clock-ramp (chip not at 2.4 GHz for short kernels)
__global__ __launch_bounds__(1024, 4)
void dereverb_phase1(const float* __restrict__ x,
                     const float* __restrict__ t60s,
                     const float* __restrict__ kw,
                     float* __restrict__ ws)
{
    const int c    = blockIdx.x >> 1;
    const int half = blockIdx.x & 1;
    const int b    = blockIdx.y;
    const int t    = threadIdx.x;

    // Per-sample kernel index (uniform): jnp.round = RNE = rintf.
    float t60 = t60s[b & 7];
    int kidx = (int)rintf(t60 * 100.0f) - 10;
    kidx = __builtin_amdgcn_readfirstlane(kidx);
    const float4* wbase = (const float4*)(kw + (size_t)kidx * (CIN * KSZ)
                                             + (size_t)c * (CPC * KSZ));

    const int qbase = half * QHALF;
    const int tq    = 2 * t;                              // 0..2046
    const int tqc   = tq < QHALF - 2 ? tq : QHALF - 2;    // clamp to 1998
    const int q     = qbase + tqc;
    const int qh    = (q + 2) < NQ ? (q + 2) : NQ;        // <= 3999

    const float* xr = x + ((size_t)b * CIN + (size_t)c * CPC) * L_IN;

    float acc[16];
    #pragma unroll
    for (int j = 0; j < 16; ++j) acc[j] = 0.0f;

    for (int rep = 0; rep < 2; ++rep) {   // diagnostic 2x pass
        const float*  xp = xr + q;
        const float*  xq = xr + qh;
        const float4* wp = wbase;

        #pragma unroll 4
        for (int ci = 0; ci < CPC; ++ci) {
            float2 a  = *(const float2*)xp;
            float  an = *xq;
            xp += L_IN;
            xq += L_IN;

            float4 w0 = wp[4 * ci + 0];   // uniform -> s_load path
            float4 w1 = wp[4 * ci + 1];
            float4 w2 = wp[4 * ci + 2];
            float4 w3 = wp[4 * ci + 3];
            const float wf[16] = {w0.x, w0.y, w0.z, w0.w, w1.x, w1.y, w1.z, w1.w,
                                  w2.x, w2.y, w2.z, w2.w, w3.x, w3.y, w3.z, w3.w};

            const float x0v[2] = {a.x, a.y};
            const float x1v[2] = {a.y, an};
            #pragma unroll
            for (int qi = 0; qi < 2; ++qi)
                #pragma unroll
                for (int r = 0; r < 8; ++r) {
                    acc[qi * 8 + r] = fmaf(x1v[qi], wf[r],     acc[qi * 8 + r]);
                    acc[qi * 8 + r] = fmaf(x0v[qi], wf[r + 8], acc[qi * 8 + r]);
                }
        }
    }

    #pragma unroll
    for (int j = 0; j < 16; ++j) acc[j] *= 0.5f;   // undo the 2x (exact)

    // Zero invalid output (global q = 3999) and clamped-tail threads.
    #pragma unroll
    for (int qi = 0; qi < 2; ++qi)
        if (qbase + tq + qi > NQ - 1)
            #pragma unroll
            for (int r = 0; r < 8; ++r) acc[qi * 8 + r] = 0.0f;

    if (tq < QHALF) {
        float* pd = ws + (size_t)b * PBSTR + (size_t)c * PSTR
                       + (size_t)8 * (qbase + tq);
        #pragma unroll
        for (int k = 0; k < 4; ++k)
            ((float4*)pd)[k] = ((const float4*)acc)[k];
    }
}

// ---------------- Phase 2: reduce 8 chunk-partials per sample ---------------
__global__ __launch_bounds__(512)
void dereverb_phase2(const float* __restrict__ ws,
                     float* __restrict__ out)
{
    const int seg = blockIdx.x;          // 16 segments of 2048 outputs
    const int b   = blockIdx.y;
    const int i   = (seg << 11) + 4 * threadIdx.x;
    if (i < LOUT) {                      // LOUT % 4 == 0 -> full float4 valid
        const float* p = ws + (size_t)b * PBSTR + i;
        float4 s = make_float4(0.f, 0.f, 0.f, 0.f);
        #pragma unroll
        for (int c = 0; c < NCH; ++c) {
            float4 v = *(const float4*)(p + c * PSTR);
            s.x += v.x; s.y += v.y; s.z += v.z; s.w += v.w;
        }
        *(float4*)(out + (size_t)b * LOUT + i) = s;
    }
}

extern "C" void kernel_launch(void* const* d_in, const int* in_sizes, int n_in,
                              void* d_out, int out_size, void* d_ws, size_t ws_size,
                              hipStream_t stream) {
    const float* x    = (const float*)d_in[0];   // (16, 512, 4000)
    const float* t60s = (const float*)d_in[1];   // (8,)
    const float* kw   = (const float*)d_in[2];   // (41, 512, 1, 16)
    float* out = (float*)d_out;                  // (16, 1, 31992)
    float* ws  = (float*)d_ws;                   // 16 MB partials

    dim3 g1(NCH * 2, 16);                        // 256 blocks, 1/CU
    dereverb_phase1<<<g1, 1024, 0, stream>>>(x, t60s, kw, ws);
    dim3 g2(16, 16);                             // 256 blocks
    dereverb_phase2<<<g2, 512, 0, stream>>>(ws, out);
}